// Round 9
// baseline (303.826 us; speedup 1.0000x reference)
//
#include <hip/hip_runtime.h>
#include <math.h>

#define N_TOKENS 32768
#define DIM      4096
#define NE       64
#define TM       32              // tokens per block
#define BKF      256             // floats per chunk per row = 1 KB (one DRAM page)
#define NCH      (DIM / BKF)     // 16 chunks
#define NBLK     (N_TOKENS / TM) // 1024
#define EPS_GAP  2e-3f
#define REFINE_BLOCKS 1024

// d_out layout (float32 elements):
//   [0, 65536)        weights  [N_TOKENS][2]
//   [65536, 131072)   indices  [N_TOKENS][2]  stored as float
//   [131072, 131136)  new_bias [64]
//
// d_ws layout (float units):
//   [0, 64)            ews_refine[64] (zeroed per call)
//   [64]               worklist count (uint, zeroed per call)
//   [128, 65664)       per-block expert partials [1024][64]
//   [65664, 98432)     worklist token ids (int)
//   [98432, 622720)    packed W frags: [c][nt][kh][hl][j][lane] 16B units
#define PART_OFF 128
#define WL_OFF   65664
#define WPK_OFF  98432

typedef __bf16 bf16x8 __attribute__((ext_vector_type(8)));
typedef float  f32x16 __attribute__((ext_vector_type(16)));

#define SB0() __builtin_amdgcn_sched_barrier(0)
#define BAR() __builtin_amdgcn_s_barrier()

// Pack W [64][4096] f32 -> bf16 hi/lo fragments ordered exactly in gate_main
// consumption order: idx = ((((c*2+nt)*2+kh)*2+hl)*8 + j)*64 + lane.
// Content: e = nt*32+(lane&31); k16 = c*16+kh*8+j; k = k16*16+(lane>>5)*8.
__global__ __launch_bounds__(256) void prep_w(
    const float* __restrict__ w, float* __restrict__ ws)
{
    const int tid  = blockIdx.x * 256 + threadIdx.x;   // 0..65535
    const int lane = tid & 63;
    const int j    = (tid >> 6) & 7;
    const int hl   = (tid >> 9) & 1;
    const int kh   = (tid >> 10) & 1;
    const int nt   = (tid >> 11) & 1;
    const int c    = tid >> 12;                        // 0..15
    const int e    = nt * 32 + (lane & 31);
    const int k    = (c * 16 + kh * 8 + j) * 16 + (lane >> 5) * 8;
    const float4 a = *(const float4*)(w + (size_t)e * DIM + k);
    const float4 b = *(const float4*)(w + (size_t)e * DIM + k + 4);
    const float v[8] = {a.x, a.y, a.z, a.w, b.x, b.y, b.z, b.w};
    __bf16 hv[8], lv[8];
    #pragma unroll
    for (int i = 0; i < 8; ++i) {
        hv[i] = (__bf16)v[i];
        lv[i] = (__bf16)(v[i] - (float)hv[i]);
    }
    ((bf16x8*)(ws + WPK_OFF))[tid] = hl ? *(bf16x8*)lv : *(bf16x8*)hv;
}

// ---- f32 -> bf16 hi/lo via truncation bit-ops ----
__device__ __forceinline__ unsigned pack_pair(float f0, float f1, float& r0, float& r1) {
    const unsigned u0 = __float_as_uint(f0), u1 = __float_as_uint(f1);
    const unsigned h0 = u0 & 0xFFFF0000u,   h1 = u1 & 0xFFFF0000u;
    r0 = f0 - __uint_as_float(h0);
    r1 = f1 - __uint_as_float(h1);
    return (u0 >> 16) | h1;
}
__device__ __forceinline__ void cvt8(const float4 a, const float4 b, uint4& h, uint4& l) {
    float r0, r1, r2, r3, r4, r5, r6, r7;
    h.x = pack_pair(a.x, a.y, r0, r1);
    h.y = pack_pair(a.z, a.w, r2, r3);
    h.z = pack_pair(b.x, b.y, r4, r5);
    h.w = pack_pair(b.z, b.w, r6, r7);
    l.x = (__float_as_uint(r0) >> 16) | (__float_as_uint(r1) & 0xFFFF0000u);
    l.y = (__float_as_uint(r2) >> 16) | (__float_as_uint(r3) & 0xFFFF0000u);
    l.z = (__float_as_uint(r4) >> 16) | (__float_as_uint(r5) & 0xFFFF0000u);
    l.w = (__float_as_uint(r6) >> 16) | (__float_as_uint(r7) & 0xFFFF0000u);
}

__device__ __forceinline__ void gload_lds16(const float* g, float* lds) {
    __builtin_amdgcn_global_load_lds(
        (const __attribute__((address_space(1))) unsigned*)g,
        (__attribute__((address_space(3))) unsigned*)lds, 16, 0, 0);
}

// Page-granular GEMM: block = 32 tokens, full K, chunk = 1 KB per row.
// One gload_lds per row per chunk (64 lanes x 16B = the row's whole 1 KB).
// Waves: nt = w&1 (expert half), kh = w>>1 (k16-half within chunk).
// FIFO per iter: [.., s_c, B_c, s_{c+1}] -> wait vmcnt(8) keeps s_{c+1} live.
__global__ __launch_bounds__(256) void gate_main(
    const float* __restrict__ x, const float* __restrict__ bias,
    float* __restrict__ out, float* __restrict__ ws)
{
    __shared__ __align__(16) float xs[2][TM * BKF];   // 2 x 32 KB
    __shared__ float sc[TM][68];
    __shared__ float part[NE];
    __shared__ float sbias[NE];

    const bf16x8* wb   = (const bf16x8*)(ws + WPK_OFF);
    unsigned* wl_count = (unsigned*)(ws + 64);
    float*    partials = ws + PART_OFF;
    int*      wl       = (int*)(ws + WL_OFF);

    const int t    = threadIdx.x;
    const int lane = t & 63;
    const int wave = t >> 6;
    const int nt   = wave & 1;
    const int kh   = wave >> 1;
    const int tb   = blockIdx.x * TM;
    const int l31  = lane & 31, lhi = lane >> 5;

    if (t < NE) { sbias[t] = bias[t]; part[t] = 0.f; }

    // stage: wave stages rows [wave*8, wave*8+8); instr i = row wave*8+i.
    // lane l covers stored 16B-slot l; logical slot = l ^ (row&15) (src-side swizzle).
    size_t sofs[8];
    #pragma unroll
    for (int i = 0; i < 8; ++i) {
        const int row = wave * 8 + i;
        sofs[i] = (size_t)(tb + row) * DIM + ((lane ^ (row & 15)) << 2);
    }

    f32x16 acc0, acc12;
    #pragma unroll
    for (int i = 0; i < 16; ++i) { acc0[i] = 0.f; acc12[i] = 0.f; }

    // prologue: stage chunk 0 -> buf 0
    #pragma unroll
    for (int i = 0; i < 8; ++i)
        gload_lds16(x + sofs[i], &xs[0][(wave * 8 + i) * BKF]);
    SB0();

    for (int c = 0; c < NCH; ++c) {
        // ---- issue B_c (16 x 1KB from L2-resident packed W) ----
        const int q = c * 4 + nt * 2 + kh;
        bf16x8 bh[8], bl[8];
        #pragma unroll
        for (int j = 0; j < 8; ++j) bh[j] = wb[(q * 2 + 0) * 512 + j * 64 + lane];
        #pragma unroll
        for (int j = 0; j < 8; ++j) bl[j] = wb[(q * 2 + 1) * 512 + j * 64 + lane];
        SB0();
        // ---- issue stage_{c+1} into the other buffer ----
        if (c + 1 < NCH) {
            #pragma unroll
            for (int i = 0; i < 8; ++i)
                gload_lds16(x + sofs[i] + (size_t)(c + 1) * BKF,
                            &xs[(c + 1) & 1][(wave * 8 + i) * BKF]);
        }
        SB0();
        // drain s_c + B_c; keep s_{c+1} (8) in flight
        if (c + 1 < NCH) { asm volatile("s_waitcnt vmcnt(8)" ::: "memory"); }
        else             { asm volatile("s_waitcnt vmcnt(0)" ::: "memory"); }
        SB0(); BAR(); SB0();

        // ---- compute chunk c from buf c&1 (pure LDS/VALU/MFMA) ----
        const float* buf = xs[c & 1];
        #pragma unroll
        for (int j = 0; j < 8; ++j) {
            const int s0 = (kh * 8 + j) * 4 + lhi * 2;        // logical 16B slot
            const float4 fa = *(const float4*)&buf[l31 * BKF + ((s0 ^ (l31 & 15)) << 2)];
            const float4 fb = *(const float4*)&buf[l31 * BKF + (((s0 + 1) ^ (l31 & 15)) << 2)];
            uint4 hh, ll;
            cvt8(fa, fb, hh, ll);
            const bf16x8 ah = __builtin_bit_cast(bf16x8, hh);
            const bf16x8 al = __builtin_bit_cast(bf16x8, ll);
            acc0  = __builtin_amdgcn_mfma_f32_32x32x16_bf16(ah, bh[j], acc0,  0, 0, 0);
            acc12 = __builtin_amdgcn_mfma_f32_32x32x16_bf16(al, bh[j], acc12, 0, 0, 0);
            acc12 = __builtin_amdgcn_mfma_f32_32x32x16_bf16(ah, bl[j], acc12, 0, 0, 0);
        }
        SB0(); BAR(); SB0();    // all waves done reading buf c&1
    }

    // ---- epilogue: merge kh halves in LDS, top-3, outputs ----
    // C/D: col = lane&31 (expert), row = (r&3)+8*(r>>2)+4*lhi (token)
    const int e = nt * 32 + l31;
    if (kh == 0) {
        #pragma unroll
        for (int r = 0; r < 16; ++r) {
            const int tok = (r & 3) + 8 * (r >> 2) + 4 * lhi;
            sc[tok][e] = acc0[r] + acc12[r];
        }
    }
    __syncthreads();
    if (kh == 1) {
        #pragma unroll
        for (int r = 0; r < 16; ++r) {
            const int tok = (r & 3) + 8 * (r >> 2) + 4 * lhi;
            sc[tok][e] += acc0[r] + acc12[r];
        }
    }
    __syncthreads();

    if (t < TM) {
        const int tok = t;
        float v1 = -3e38f, v2 = -3e38f, v3 = -3e38f;
        int   i1 = 0,      i2 = 0;
        #pragma unroll 8
        for (int ei = 0; ei < NE; ++ei) {
            const float s = sc[tok][ei] + sbias[ei];
            if (s > v1)      { v3 = v2; v2 = v1; i2 = i1; v1 = s; i1 = ei; }
            else if (s > v2) { v3 = v2; v2 = s;  i2 = ei; }
            else if (s > v3) { v3 = s; }
        }
        const bool risky = (v1 - v2 < EPS_GAP) || (v2 - v3 < EPS_GAP);
        if (risky) {
            const int pos = (int)atomicAdd(wl_count, 1u);
            wl[pos] = tb + tok;                  // refined later in fp64
        } else {
            const float ex = expf(v2 - v1);      // <= 1
            const float w1 = 1.f / (1.f + ex);
            const float w2 = ex * w1;
            const size_t g = (size_t)(tb + tok) * 2;
            *(float2*)(out + g)                        = make_float2(w1, w2);
            *(float2*)(out + (size_t)N_TOKENS * 2 + g) = make_float2((float)i1, (float)i2);
            atomicAdd(&part[i1], w1);
            atomicAdd(&part[i2], w2);
        }
    }
    __syncthreads();
    if (t < NE) partials[(size_t)blockIdx.x * NE + t] = part[t];
}

// fp64 re-score of near-tie tokens: exact ordering vs the true scores.
__global__ __launch_bounds__(256) void gate_refine(
    const float* __restrict__ x,
    const float* __restrict__ w,
    const float* __restrict__ bias,
    float* __restrict__ out,
    float* __restrict__ ws)
{
    float*          ews_ref  = ws;
    const unsigned* wl_count = (const unsigned*)(ws + 64);
    const int*      wl       = (const int*)(ws + WL_OFF);

    const int t = threadIdx.x;
    const int e = t >> 2;        // expert 0..63
    const int q = t & 3;         // quarter of K
    __shared__ double sc[NE];

    const unsigned count = *wl_count;
    for (unsigned it = blockIdx.x; it < count; it += gridDim.x) {
        const int tok = wl[it];
        const float* xr = x + (size_t)tok * DIM;
        const float* wr = w + (size_t)e * DIM;
        double s = 0.0;
        const int k0 = q * (DIM / 4), k1 = k0 + DIM / 4;
        for (int k = k0; k < k1; k += 4) {
            const float4 a = *(const float4*)(xr + k);
            const float4 b = *(const float4*)(wr + k);
            s += (double)a.x * (double)b.x;
            s += (double)a.y * (double)b.y;
            s += (double)a.z * (double)b.z;
            s += (double)a.w * (double)b.w;
        }
        s += __shfl_xor(s, 1);
        s += __shfl_xor(s, 2);
        if (q == 0) sc[e] = s + (double)bias[e];
        __syncthreads();

        if (t == 0) {
            double v1 = -1e300, v2 = -1e300;
            int i1 = 0, i2 = 0;
            for (int j = 0; j < NE; ++j) {
                const double sv = sc[j];
                if (sv > v1)      { v2 = v1; i2 = i1; v1 = sv; i1 = j; }
                else if (sv > v2) { v2 = sv; i2 = j; }
            }
            const double ex = exp(v2 - v1);
            const double w1 = 1.0 / (1.0 + ex);
            const double w2 = ex * w1;
            const size_t g = (size_t)tok * 2;
            *(float2*)(out + g)                        = make_float2((float)w1, (float)w2);
            *(float2*)(out + (size_t)N_TOKENS * 2 + g) = make_float2((float)i1, (float)i2);
            atomicAdd(&ews_ref[i1], (float)w1);
            atomicAdd(&ews_ref[i2], (float)w2);
        }
        __syncthreads();
    }
}

__global__ __launch_bounds__(256) void gate_bias(
    const float* __restrict__ bias,
    const float* __restrict__ target,
    const float* __restrict__ ws,
    float* __restrict__ out)
{
    __shared__ float red[4][NE];
    const int t = threadIdx.x;
    const int e = t & 63, seg = t >> 6;
    const float* partials = ws + PART_OFF;
    float v = 0.f;
    for (int b = seg * 256; b < seg * 256 + 256; ++b)
        v += partials[(size_t)b * NE + e];
    red[seg][e] = v;
    __syncthreads();
    if (t < NE) {
        const float vv = red[0][t] + red[1][t] + red[2][t] + red[3][t] + ws[t];
        float total = vv;
        #pragma unroll
        for (int off = 32; off > 0; off >>= 1)
            total += __shfl_xor(total, off);
        const float nb = bias[t] + 0.001f * ((target[t] * total - vv) / total);
        out[(size_t)N_TOKENS * 4 + t] = nb;
    }
}

extern "C" void kernel_launch(void* const* d_in, const int* in_sizes, int n_in,
                              void* d_out, int out_size, void* d_ws, size_t ws_size,
                              hipStream_t stream) {
    const float* x      = (const float*)d_in[0];
    const float* w      = (const float*)d_in[1];
    const float* bias   = (const float*)d_in[2];
    const float* target = (const float*)d_in[3];
    float* out = (float*)d_out;
    float* ws  = (float*)d_ws;

    hipMemsetAsync(ws, 0, 128 * sizeof(float), stream);   // ews_ref + wl_count
    prep_w     <<<256, 256, 0, stream>>>(w, ws);
    gate_main  <<<NBLK, 256, 0, stream>>>(x, bias, out, ws);
    gate_refine<<<REFINE_BLOCKS, 256, 0, stream>>>(x, w, bias, out, ws);
    gate_bias  <<<1, 256, 0, stream>>>(bias, target, ws, out);
}